// Round 3
// baseline (171.154 us; speedup 1.0000x reference)
//
#include <hip/hip_runtime.h>

typedef float f32x4 __attribute__((ext_vector_type(4)));
typedef float f32x2 __attribute__((ext_vector_type(2)));
typedef short bf16x8 __attribute__((ext_vector_type(8)));

#define LOG2E 1.4426950408889634f

__device__ __forceinline__ unsigned short f2bf(float f) {
  return __builtin_bit_cast(unsigned short, (__bf16)f);
}

// ---------------------------------------------------------------------------
// ws layout:
//   [0]      double accum
//   [16]     unsigned done
//   [1024]   float partialT[256][64]  (column-sum partials, transposed)
//   [66560]  float sq[8192]
//   [131072] ushort Vbf[8192*256]     (bf16 cache of concat(src,tgt))
// ---------------------------------------------------------------------------

// K1: fused prep — per-row sum-of-squares, bf16 cast, per-block column sums.
// 64 blocks x 256 threads; block b owns rows [128b, 128b+128), wave w owns 32.
// Also zeroes accum/done (stream order guarantees visibility to k_main).
__global__ __launch_bounds__(256) void k_prep(
    const float* __restrict__ src, const float* __restrict__ tgt,
    float* __restrict__ sq, unsigned short* __restrict__ Vbf,
    float* __restrict__ partialT, double* __restrict__ accum,
    unsigned int* __restrict__ done) {
  const int t = threadIdx.x, lane = t & 63, w = t >> 6, b = blockIdx.x;
  if (b == 0 && t == 0) { *accum = 0.0; *done = 0u; }
  const int row0 = b * 128 + w * 32;
  f32x4 colacc = {0.f, 0.f, 0.f, 0.f};
  for (int i = 0; i < 32; ++i) {
    const int row = row0 + i;
    const float* rowp = (row < 4096) ? src + (size_t)row * 256
                                     : tgt + (size_t)(row - 4096) * 256;
    float4 v = ((const float4*)rowp)[lane];
    colacc[0] += v.x; colacc[1] += v.y; colacc[2] += v.z; colacc[3] += v.w;
    float ss = v.x * v.x + v.y * v.y + v.z * v.z + v.w * v.w;
    #pragma unroll
    for (int m = 32; m >= 1; m >>= 1) ss += __shfl_xor(ss, m, 64);
    if (lane == 0) sq[row] = ss;
    ushort4 p;
    p.x = f2bf(v.x); p.y = f2bf(v.y); p.z = f2bf(v.z); p.w = f2bf(v.w);
    ((ushort4*)Vbf)[(size_t)row * 64 + lane] = p;
  }
  __shared__ float cpart[4][256];
  *(f32x4*)&cpart[w][lane * 4] = colacc;
  __syncthreads();
  const float pt = cpart[0][t] + cpart[1][t] + cpart[2][t] + cpart[3][t];
  partialT[t * 64 + b] = pt;   // transposed: column t, block-slab b
}

// ---------------------------------------------------------------------------
// K2: main — per-block bandwidth recompute + tiled bf16 MFMA Gram +
// fused 5-kernel gaussian (1 exp2 + 4 squarings) + signed reduce +
// last-block finalization. 1D grid of exactly 2080 upper-triangular tiles.
// ---------------------------------------------------------------------------
__global__ __launch_bounds__(256, 4) void k_main(
    const unsigned short* __restrict__ Vbf, const float* __restrict__ sq,
    const float* __restrict__ partialT, double* __restrict__ accum,
    unsigned int* __restrict__ done, float* __restrict__ out) {
  // ---- decode linear block id -> (brow=r, bcol=c), upper triangle of 64x64 ----
  const int bid = blockIdx.x;
  int r = (int)((129.0f - sqrtf(16641.0f - 8.0f * (float)bid)) * 0.5f);
  int base = (r * (129 - r)) >> 1;
  if (bid < base)                 { --r; base = (r * (129 - r)) >> 1; }
  else if (bid - base >= 64 - r)  { ++r; base = (r * (129 - r)) >> 1; }
  const int c = r + (bid - base);
  const int i0 = r * 128;
  const int j0 = c * 128;

  const int t = threadIdx.x;
  const int lane = t & 63;
  const int w = t >> 6;
  const int wr = w >> 1;
  const int wc = w & 1;

  __shared__ uint4 lds4[2048];           // exactly 32 KB
  char* As = (char*)lds4;
  char* Bs = (char*)lds4 + 16384;
  float* redf = (float*)lds4;            // aliases As (used outside K-loop only)

  // ---- per-block bandwidth: sum_l2 = 2*n*S - 2*||colsum||^2 ----
  float Sp = 0.f;
  #pragma unroll
  for (int j = 0; j < 8; ++j) {
    float4 q = ((const float4*)sq)[t + 256 * j];
    Sp += q.x + q.y + q.z + q.w;
  }
  float csum = 0.f;
  #pragma unroll
  for (int j = 0; j < 16; ++j) {
    float4 q = ((const float4*)(partialT + t * 64))[j];
    csum += q.x + q.y + q.z + q.w;
  }
  float Cp = csum * csum;
  #pragma unroll
  for (int m = 32; m >= 1; m >>= 1) {
    Sp += __shfl_xor(Sp, m, 64);
    Cp += __shfl_xor(Cp, m, 64);
  }
  if (lane == 0) { redf[w] = Sp; redf[4 + w] = Cp; }
  __syncthreads();
  {
    const float S   = redf[0] + redf[1] + redf[2] + redf[3];
    const float CSQ = redf[4] + redf[5] + redf[6] + redf[7];
    const float sum_l2 = 2.f * 8192.f * S - 2.f * CSQ;
    // bandwidth = sum_l2/(n^2-n) / 4 ; nc0s = -log2(e)/bw / 16
    const float bw = sum_l2 / (8192.f * 8192.f - 8192.f) * 0.25f;
    const float nc0s = -LOG2E / bw * 0.0625f;

    const unsigned short* VA = Vbf + (size_t)i0 * 256;
    const unsigned short* VB = Vbf + (size_t)j0 * 256;

    f32x4 acc[4][4] = {};
    const int srow = t >> 3;               // 0..31
    const int scb  = (t & 7) * 16;         // byte offset in 128B slab

    for (int ks = 0; ks < 4; ++ks) {
      const int kc = ks * 64;
      __syncthreads();
      #pragma unroll
      for (int it = 0; it < 4; ++it) {
        const int rr = it * 32 + srow;
        const int dst = rr * 128 + (scb ^ ((rr & 7) << 4));
        uint4 ga = *(const uint4*)(VA + (size_t)rr * 256 + kc + (scb >> 1));
        uint4 gb = *(const uint4*)(VB + (size_t)rr * 256 + kc + (scb >> 1));
        *(uint4*)(As + dst) = ga;
        *(uint4*)(Bs + dst) = gb;
      }
      __syncthreads();
      #pragma unroll
      for (int kk = 0; kk < 2; ++kk) {
        const int kbyte = kk * 64 + ((lane >> 4) << 4);
        bf16x8 a[4], b[4];
        #pragma unroll
        for (int m = 0; m < 4; ++m) {
          const int ra = wr * 64 + m * 16 + (lane & 15);
          a[m] = *(const bf16x8*)(As + ra * 128 + (kbyte ^ ((ra & 7) << 4)));
          const int rb = wc * 64 + m * 16 + (lane & 15);
          b[m] = *(const bf16x8*)(Bs + rb * 128 + (kbyte ^ ((rb & 7) << 4)));
        }
        #pragma unroll
        for (int m = 0; m < 4; ++m)
          #pragma unroll
          for (int n = 0; n < 4; ++n)
            acc[m][n] = __builtin_amdgcn_mfma_f32_16x16x32_bf16(a[m], b[n], acc[m][n], 0, 0, 0);
      }
    }

    // ---- epilogue: l2 -> e=exp2(tt/16) -> e+e^2+e^4+e^8+e^16, signed sum ----
    float rsv[16];
    const int rbase = i0 + wr * 64 + ((lane >> 4) << 2);
    #pragma unroll
    for (int m = 0; m < 4; ++m) {
      const float4 q = *(const float4*)(sq + rbase + m * 16);
      rsv[m * 4 + 0] = q.x; rsv[m * 4 + 1] = q.y;
      rsv[m * 4 + 2] = q.z; rsv[m * 4 + 3] = q.w;
    }
    float cs[4];
    const int cbase = j0 + wc * 64 + (lane & 15);
    #pragma unroll
    for (int n = 0; n < 4; ++n) cs[n] = sq[cbase + n * 16];

    f32x2 ks2 = {0.f, 0.f};
    #pragma unroll
    for (int m = 0; m < 4; ++m)
      #pragma unroll
      for (int n = 0; n < 4; ++n)
        #pragma unroll
        for (int h = 0; h < 2; ++h) {
          f32x2 g  = { acc[m][n][2 * h], acc[m][n][2 * h + 1] };
          f32x2 rc = { rsv[m * 4 + 2 * h] + cs[n], rsv[m * 4 + 2 * h + 1] + cs[n] };
          f32x2 l2 = __builtin_elementwise_max(rc - 2.f * g, (f32x2){0.f, 0.f});
          f32x2 tt = l2 * nc0s;
          f32x2 e;
          e[0] = __builtin_amdgcn_exp2f(tt[0]);
          e[1] = __builtin_amdgcn_exp2f(tt[1]);
          f32x2 s = e;
          f32x2 e2 = e * e;   s += e2;
          f32x2 e4 = e2 * e2; s += e4;
          f32x2 e8 = e4 * e4; s += e8;
          s += e8 * e8;
          ks2 += s;
        }
    float ksum = ks2[0] + ks2[1];
    #pragma unroll
    for (int m = 32; m >= 1; m >>= 1) ksum += __shfl_xor(ksum, m, 64);

    __syncthreads();                        // all waves done with LDS tiles
    if (lane == 0) redf[w] = ksum;
    __syncthreads();
    if (t == 0) {
      const float sign = ((r < 32) == (c < 32)) ? 1.0f : -1.0f;
      const float mult = (r == c) ? 1.0f : 2.0f;
      const double contrib =
          (double)((redf[0] + redf[1] + redf[2] + redf[3]) * sign * mult);
      atomicAdd(accum, contrib);
      __threadfence();
      const unsigned int old = atomicAdd(done, 1u);
      if (old == 2079u) {
        __threadfence();
        const double tot = atomicAdd(accum, 0.0);   // coherent read-back
        out[0] = (float)(tot * (1.0 / 16777216.0));
      }
    }
  }
}

// ---------------------------------------------------------------------------
extern "C" void kernel_launch(void* const* d_in, const int* in_sizes, int n_in,
                              void* d_out, int out_size, void* d_ws, size_t ws_size,
                              hipStream_t stream) {
  const float* src = (const float*)d_in[0];
  const float* tgt = (const float*)d_in[1];
  char* ws = (char*)d_ws;
  double*         accum    = (double*)ws;
  unsigned int*   done     = (unsigned int*)(ws + 16);
  float*          partialT = (float*)(ws + 1024);
  float*          sq       = (float*)(ws + 66560);
  unsigned short* Vbf      = (unsigned short*)(ws + 131072);
  float* out = (float*)d_out;

  hipLaunchKernelGGL(k_prep, dim3(64),   dim3(256), 0, stream,
                     src, tgt, sq, Vbf, partialT, accum, done);
  hipLaunchKernelGGL(k_main, dim3(2080), dim3(256), 0, stream,
                     Vbf, sq, partialT, accum, done, out);
}

// Round 5
// 142.807 us; speedup vs baseline: 1.1985x; 1.1985x over previous
//
#include <hip/hip_runtime.h>

typedef float f32x4 __attribute__((ext_vector_type(4)));
typedef float f32x2 __attribute__((ext_vector_type(2)));
typedef short bf16x8 __attribute__((ext_vector_type(8)));

#define LOG2E 1.4426950408889634f

// global -> LDS direct DMA, 16B per lane; dest = wave-uniform base + lane*16
#define GLDS16(g, l) __builtin_amdgcn_global_load_lds(                       \
    (const __attribute__((address_space(1))) void*)(g),                      \
    (__attribute__((address_space(3))) void*)(l), 16, 0, 0)

__device__ __forceinline__ unsigned short f2bf(float f) {
  return __builtin_bit_cast(unsigned short, (__bf16)f);
}

// ---------------------------------------------------------------------------
// ws layout:
//   [0]    double accum          (zeroed by memset node)
//   [16]   uint   done_main      (zeroed by memset node)
//   [24]   uint   done_prep      (zeroed by memset node)
//   [32]   float  nc0s           (written by k_prep last block)
//   [512]  float  Spart[64]
//   [1024] float  partialT[256][64]   (column-sum partials, transposed)
//   [66560]  float sq[8192]
//   [131072] ushort Vbf[8192*256]     (bf16 cache of concat(src,tgt))
// ---------------------------------------------------------------------------

// K1: prep — row sum-of-squares, bf16 cast, column-sum partials; the LAST
// block (done-counter) reduces partials to the bandwidth constant nc0s.
// 64 blocks x 1024 threads; block b owns rows [128b,128b+128), wave w owns 8.
__global__ __launch_bounds__(1024) void k_prep(
    const float* __restrict__ src, const float* __restrict__ tgt,
    float* __restrict__ sq, unsigned short* __restrict__ Vbf,
    float* __restrict__ partialT, float* __restrict__ Spart,
    unsigned int* __restrict__ done_prep, float* __restrict__ nc0sp) {
  const int t = threadIdx.x, lane = t & 63, w = t >> 6, b = blockIdx.x;
  __shared__ float cpart[16][256];
  __shared__ float sredS[16];
  __shared__ unsigned int islast;
  __shared__ float sS;

  const int row0 = b * 128 + w * 8;
  f32x4 colacc = {0.f, 0.f, 0.f, 0.f};
  float Sp = 0.f;
  for (int i = 0; i < 8; ++i) {
    const int row = row0 + i;
    const float* rowp = (row < 4096) ? src + (size_t)row * 256
                                     : tgt + (size_t)(row - 4096) * 256;
    float4 v = ((const float4*)rowp)[lane];
    colacc[0] += v.x; colacc[1] += v.y; colacc[2] += v.z; colacc[3] += v.w;
    float ss = v.x * v.x + v.y * v.y + v.z * v.z + v.w * v.w;
    #pragma unroll
    for (int m = 32; m >= 1; m >>= 1) ss += __shfl_xor(ss, m, 64);
    if (lane == 0) { sq[row] = ss; Sp += ss; }
    ushort4 p;
    p.x = f2bf(v.x); p.y = f2bf(v.y); p.z = f2bf(v.z); p.w = f2bf(v.w);
    ((ushort4*)Vbf)[(size_t)row * 64 + lane] = p;
  }
  *(f32x4*)&cpart[w][lane * 4] = colacc;
  if (lane == 0) sredS[w] = Sp;
  __syncthreads();
  if (t < 256) {
    float pt = 0.f;
    #pragma unroll
    for (int ww = 0; ww < 16; ++ww) pt += cpart[ww][t];
    partialT[t * 64 + b] = pt;
  }
  if (t == 0) {
    float s = 0.f;
    #pragma unroll
    for (int ww = 0; ww < 16; ++ww) s += sredS[ww];
    Spart[b] = s;
  }
  __syncthreads();               // drains this block's global stores (vmcnt)
  if (t == 0) {
    __threadfence();             // release
    islast = (atomicAdd(done_prep, 1u) == 63u) ? 1u : 0u;
  }
  __syncthreads();
  if (islast) {
    __threadfence();             // acquire before reading other blocks' stores
    const int col = t & 255, seg = t >> 8;
    float cs = 0.f;
    #pragma unroll
    for (int j = 0; j < 16; ++j) cs += partialT[col * 64 + seg * 16 + j];
    cpart[seg][col] = cs;
    __syncthreads();
    float Cp = 0.f, Sv = 0.f;
    if (t < 256) {
      const float ctot = cpart[0][t] + cpart[1][t] + cpart[2][t] + cpart[3][t];
      Cp = ctot * ctot;
    }
    if (t < 64) Sv = Spart[t];
    #pragma unroll
    for (int m = 32; m >= 1; m >>= 1) {
      Cp += __shfl_xor(Cp, m, 64);
      Sv += __shfl_xor(Sv, m, 64);
    }
    if (lane == 0) sredS[w] = Cp;
    if (t == 0) sS = Sv;
    __syncthreads();
    if (t == 0) {
      const float CSQ = sredS[0] + sredS[1] + sredS[2] + sredS[3];
      const float sum_l2 = 2.f * 8192.f * sS - 2.f * CSQ;
      const float bw = sum_l2 / (8192.f * 8192.f - 8192.f) * 0.25f;
      *nc0sp = -LOG2E / bw * 0.0625f;   // -log2(e)/bw/16 (exp2-squaring form)
    }
  }
}

// ---------------------------------------------------------------------------
// K2: main — bf16 MFMA Gram (128x128 tile, 4 waves 2x2, BK=32, double-buffered
// global_load_lds staging with source-side XOR swizzle) + fused 5-kernel
// gaussian (1 exp2 + 4 squarings) + signed reduce + last-block finalize.
// Grid: exactly 2080 upper-triangular tiles.
// ---------------------------------------------------------------------------
__global__ __launch_bounds__(256) void k_main(
    const unsigned short* __restrict__ Vbf, const float* __restrict__ sq,
    const float* __restrict__ nc0sp, double* __restrict__ accum,
    unsigned int* __restrict__ done, float* __restrict__ out) {
  // decode linear block id -> (r,c) in upper triangle of 64x64
  const int bid = blockIdx.x;
  int r = (int)((129.0f - sqrtf(16641.0f - 8.0f * (float)bid)) * 0.5f);
  int base = (r * (129 - r)) >> 1;
  if (bid < base)                { --r; base = (r * (129 - r)) >> 1; }
  else if (bid - base >= 64 - r) { ++r; base = (r * (129 - r)) >> 1; }
  const int c = r + (bid - base);
  const int i0 = r * 128, j0 = c * 128;

  const int t = threadIdx.x, lane = t & 63, w = t >> 6;
  const int wr = w >> 1, wc = w & 1;

  __shared__ uint4 lds4[2048];           // 32 KB: [buf][A 8K | B 8K]
  char* lds = (char*)lds4;
  float* redf = (float*)lds4;            // reused after the K-loop only

  const char* VAb = (const char*)(Vbf + (size_t)i0 * 256);
  const char* VBb = (const char*)(Vbf + (size_t)j0 * 256);

  // staging source offset: lane covers row rr0=w*32+(lane>>2), slot lane&3;
  // source slot pre-XORed by ((rr>>1)&3) so linear LDS ends up swizzled.
  // second 16-row group is the same pattern at +16*512 source bytes.
  const int rr0   = w * 32 + (lane >> 2);
  const int soff0 = rr0 * 512 + (((lane & 3) ^ ((rr0 >> 1) & 3)) << 4);

  f32x4 acc[4][4] = {};

  { // prologue: stage ks=0 into buf 0
    char* Al = lds + w * 2048;
    char* Bl = Al + 8192;
    GLDS16(VAb + soff0, Al);
    GLDS16(VAb + soff0 + 8192, Al + 1024);
    GLDS16(VBb + soff0, Bl);
    GLDS16(VBb + soff0 + 8192, Bl + 1024);
  }
  __syncthreads();   // emits vmcnt(0) wait + barrier: buf0 ready

  int buf = 0;
  const int sl = lane >> 4;              // wanted k-slot within 64B row
  #pragma unroll
  for (int ks = 0; ks < 8; ++ks) {
    if (ks < 7) {                        // stage next slab into other buffer
      const int o = soff0 + (ks + 1) * 64;
      char* Al = lds + (buf ^ 1) * 16384 + w * 2048;
      char* Bl = Al + 8192;
      GLDS16(VAb + o, Al);
      GLDS16(VAb + o + 8192, Al + 1024);
      GLDS16(VBb + o, Bl);
      GLDS16(VBb + o + 8192, Bl + 1024);
    }
    const char* Ab = lds + buf * 16384;
    const char* Bb = Ab + 8192;
    bf16x8 a[4], b[4];
    #pragma unroll
    for (int m = 0; m < 4; ++m) {
      const int ra = wr * 64 + m * 16 + (lane & 15);
      a[m] = *(const bf16x8*)(Ab + ra * 64 + ((sl ^ ((ra >> 1) & 3)) << 4));
      const int rb = wc * 64 + m * 16 + (lane & 15);
      b[m] = *(const bf16x8*)(Bb + rb * 64 + ((sl ^ ((rb >> 1) & 3)) << 4));
    }
    #pragma unroll
    for (int m = 0; m < 4; ++m)
      #pragma unroll
      for (int n = 0; n < 4; ++n)
        acc[m][n] = __builtin_amdgcn_mfma_f32_16x16x32_bf16(a[m], b[n], acc[m][n], 0, 0, 0);
    __syncthreads();                     // vmcnt(0)+lgkmcnt(0)+barrier
    buf ^= 1;
  }

  // ---- epilogue: l2 -> e=exp2(l2*nc0s) -> e+e^2+e^4+e^8+e^16, signed sum ----
  const float nc0s = *nc0sp;
  float rsv[16];
  const int rbase = i0 + wr * 64 + ((lane >> 4) << 2);
  #pragma unroll
  for (int m = 0; m < 4; ++m) {
    const float4 q = *(const float4*)(sq + rbase + m * 16);
    rsv[m * 4 + 0] = q.x; rsv[m * 4 + 1] = q.y;
    rsv[m * 4 + 2] = q.z; rsv[m * 4 + 3] = q.w;
  }
  float cs[4];
  const int cbase = j0 + wc * 64 + (lane & 15);
  #pragma unroll
  for (int n = 0; n < 4; ++n) cs[n] = sq[cbase + n * 16];

  f32x2 ks2 = {0.f, 0.f};
  #pragma unroll
  for (int m = 0; m < 4; ++m)
    #pragma unroll
    for (int n = 0; n < 4; ++n)
      #pragma unroll
      for (int h = 0; h < 2; ++h) {
        f32x2 g  = { acc[m][n][2 * h], acc[m][n][2 * h + 1] };
        f32x2 rc = { rsv[m * 4 + 2 * h] + cs[n], rsv[m * 4 + 2 * h + 1] + cs[n] };
        f32x2 l2 = __builtin_elementwise_max(rc - 2.f * g, (f32x2){0.f, 0.f});
        f32x2 tt = l2 * nc0s;
        f32x2 e;
        e[0] = __builtin_amdgcn_exp2f(tt[0]);
        e[1] = __builtin_amdgcn_exp2f(tt[1]);
        f32x2 s = e;
        f32x2 e2 = e * e;   s += e2;
        f32x2 e4 = e2 * e2; s += e4;
        f32x2 e8 = e4 * e4; s += e8;
        s += e8 * e8;
        ks2 += s;
      }
  float ksum = ks2[0] + ks2[1];
  #pragma unroll
  for (int m = 32; m >= 1; m >>= 1) ksum += __shfl_xor(ksum, m, 64);

  if (lane == 0) redf[w] = ksum;
  __syncthreads();
  if (t == 0) {
    const float sign = ((r < 32) == (c < 32)) ? 1.0f : -1.0f;
    const float mult = (r == c) ? 1.0f : 2.0f;
    const double contrib =
        (double)((redf[0] + redf[1] + redf[2] + redf[3]) * sign * mult);
    atomicAdd(accum, contrib);
    __threadfence();
    const unsigned int old = atomicAdd(done, 1u);
    if (old == 2079u) {
      __threadfence();
      const double tot = atomicAdd(accum, 0.0);   // coherent read-back
      out[0] = (float)(tot * (1.0 / 16777216.0));
    }
  }
}

// ---------------------------------------------------------------------------
extern "C" void kernel_launch(void* const* d_in, const int* in_sizes, int n_in,
                              void* d_out, int out_size, void* d_ws, size_t ws_size,
                              hipStream_t stream) {
  const float* src = (const float*)d_in[0];
  const float* tgt = (const float*)d_in[1];
  char* ws = (char*)d_ws;
  double*         accum     = (double*)ws;
  unsigned int*   done_main = (unsigned int*)(ws + 16);
  unsigned int*   done_prep = (unsigned int*)(ws + 24);
  float*          nc0s      = (float*)(ws + 32);
  float*          Spart     = (float*)(ws + 512);
  float*          partialT  = (float*)(ws + 1024);
  float*          sq        = (float*)(ws + 66560);
  unsigned short* Vbf       = (unsigned short*)(ws + 131072);
  float* out = (float*)d_out;

  hipMemsetAsync(ws, 0, 64, stream);   // accum, done_main, done_prep, nc0s
  hipLaunchKernelGGL(k_prep, dim3(64),   dim3(1024), 0, stream,
                     src, tgt, sq, Vbf, partialT, Spart, done_prep, nc0s);
  hipLaunchKernelGGL(k_main, dim3(2080), dim3(256),  0, stream,
                     Vbf, sq, nc0s, accum, done_main, out);
}